// Round 2
// baseline (1227.734 us; speedup 1.0000x reference)
//
#include <hip/hip_runtime.h>
#include <hip/hip_bf16.h>
#include <math.h>

// Shapes (fixed by problem): B=2, S=2048, D_EMBED=D_MODEL=1024, H=16, DEPTH=64.
// Reference quirk: scores = V_proj . K_proj^T / 8 ; attn = probs . Q_proj ; out = attn @ wf + bf
// Outputs concatenated: out [2,2048,1024] f32, then probs [2,16,2048,2048] f32.

typedef float f32x4 __attribute__((ext_vector_type(4)));
typedef __bf16 bf16x8 __attribute__((ext_vector_type(8)));
typedef __bf16 bf16x4 __attribute__((ext_vector_type(4)));

#define LOG2E 1.44269504088896340736f

static __device__ __forceinline__ f32x4 mfma16x16x32(bf16x8 a, bf16x8 b, f32x4 c) {
    return __builtin_amdgcn_mfma_f32_16x16x32_bf16(a, b, c, 0, 0, 0);
}

// ---------------- Kernel 1: transpose+cast 4 weight matrices to bf16 [n][k] ----------------
__global__ void __launch_bounds__(256) wtrans_kernel(
    const float* __restrict__ w0, const float* __restrict__ w1,
    const float* __restrict__ w2, const float* __restrict__ w3,
    __bf16* __restrict__ o0, __bf16* __restrict__ o1,
    __bf16* __restrict__ o2, __bf16* __restrict__ o3)
{
    const float* W; __bf16* O;
    switch (blockIdx.z) {
        case 0: W = w0; O = o0; break;
        case 1: W = w1; O = o1; break;
        case 2: W = w2; O = o2; break;
        default: W = w3; O = o3; break;
    }
    __shared__ float tile[32][33];
    int tx = threadIdx.x, ty = threadIdx.y;           // block (32,8)
    int n0 = blockIdx.x * 32, k0 = blockIdx.y * 32;
    #pragma unroll
    for (int j = 0; j < 32; j += 8)
        tile[ty + j][tx] = W[(size_t)(k0 + ty + j) * 1024 + n0 + tx];
    __syncthreads();
    #pragma unroll
    for (int j = 0; j < 32; j += 8)
        O[(size_t)(n0 + ty + j) * 1024 + k0 + tx] = (__bf16)tile[tx][ty + j];
}

// ---------------- Kernel 2: projection GEMM  C = X(f32) @ Wt^T + bias -> bf16 ----------------
// Wt is [n][k] (pre-transposed). outN: natural [4096][1024]. outQt: per-head transposed
// [B][H][64][2048] (exactly one of outN/outQt is non-null).
// Grid (16, 64): x = n-panel (64 wide), y = m-panel (64 rows). 4 waves, each 16(m) x 64(n).
__global__ void __launch_bounds__(256) proj_gemm(
    const float* __restrict__ X, const __bf16* __restrict__ Wt,
    const float* __restrict__ bias, __bf16* __restrict__ outN,
    __bf16* __restrict__ outQt)
{
    int lane = threadIdx.x & 63, wid = threadIdx.x >> 6;
    int g = lane >> 4, sl = lane & 15;
    int bm0 = blockIdx.y * 64, bn0 = blockIdx.x * 64;
    int arow = bm0 + wid * 16 + sl;

    f32x4 acc[4] = {};
    const float* ap = X + (size_t)arow * 1024 + g * 8;
    const __bf16* bp0 = Wt + (size_t)(bn0 + sl) * 1024 + g * 8;

    for (int kk = 0; kk < 32; ++kk) {
        f32x4 x0 = *(const f32x4*)(ap);
        f32x4 x1 = *(const f32x4*)(ap + 4);
        ap += 32;
        bf16x8 a;
        a[0]=(__bf16)x0[0]; a[1]=(__bf16)x0[1]; a[2]=(__bf16)x0[2]; a[3]=(__bf16)x0[3];
        a[4]=(__bf16)x1[0]; a[5]=(__bf16)x1[1]; a[6]=(__bf16)x1[2]; a[7]=(__bf16)x1[3];
        #pragma unroll
        for (int nt = 0; nt < 4; ++nt) {
            bf16x8 b = *(const bf16x8*)(bp0 + (size_t)nt * 16 * 1024 + kk * 32);
            acc[nt] = mfma16x16x32(a, b, acc[nt]);
        }
    }
    #pragma unroll
    for (int nt = 0; nt < 4; ++nt) {
        int n = bn0 + nt * 16 + sl;
        float bv = bias[n];
        #pragma unroll
        for (int r = 0; r < 4; ++r) {
            int mrow = bm0 + wid * 16 + g * 4 + r;   // C: row=(lane>>4)*4+r, col=lane&15
            float vv = acc[nt][r] + bv;
            if (outQt) {
                int b = mrow >> 11, s = mrow & 2047;
                int h = n >> 6, d = n & 63;
                outQt[((size_t)((b * 16 + h) * 64 + d)) * 2048 + s] = (__bf16)vv;
            } else {
                outN[(size_t)mrow * 1024 + n] = (__bf16)vv;
            }
        }
    }
}

// ---------------- Kernel 3: fused flash attention (scores -> softmax -> probs + PV) --------
// Per wave: 16 s-rows of one (b,h). Swapped QK^T: c = mfma(K_frag, V_frag) gives scoresT,
// so lane (g,sl) holds s = sl (fixed) and t = tile*16 + g*4 + {0..3} -> softmax is lane-local.
__global__ void __launch_bounds__(256) flash_attn(
    const __bf16* __restrict__ Qt, const __bf16* __restrict__ Kp,
    const __bf16* __restrict__ Vp, float* __restrict__ probs,
    __bf16* __restrict__ attn)
{
    __shared__ __bf16 pl[4][16][40];   // per-wave p-tile bounce, 80B row stride (2-way banks)
    int lane = threadIdx.x & 63, wid = threadIdx.x >> 6;
    int g = lane >> 4, sl = lane & 15;
    int bh = blockIdx.y, b = bh >> 4, h = bh & 15;
    int s0 = blockIdx.x * 64 + wid * 16;

    const __bf16* kbase  = Kp + (size_t)b * 2048 * 1024 + h * 64;
    const __bf16* vbase  = Vp + (size_t)b * 2048 * 1024 + h * 64;
    const __bf16* qtbase = Qt + (size_t)bh * 64 * 2048;

    const __bf16* vp = vbase + (size_t)(s0 + sl) * 1024 + g * 8;
    bf16x8 vlo = *(const bf16x8*)(vp);
    bf16x8 vhi = *(const bf16x8*)(vp + 32);

    // ---- phase 1: online row max / sum over all t ----
    float m = -INFINITY, lsum = 0.f;
    for (int tt = 0; tt < 128; ++tt) {
        const __bf16* kp = kbase + (size_t)(tt * 16 + sl) * 1024 + g * 8;
        bf16x8 klo = *(const bf16x8*)(kp);
        bf16x8 khi = *(const bf16x8*)(kp + 32);
        f32x4 c = {0.f, 0.f, 0.f, 0.f};
        c = mfma16x16x32(klo, vlo, c);
        c = mfma16x16x32(khi, vhi, c);
        float v0 = c[0]*0.125f, v1 = c[1]*0.125f, v2 = c[2]*0.125f, v3 = c[3]*0.125f;
        float tmax = fmaxf(fmaxf(v0, v1), fmaxf(v2, v3));
        float mn = fmaxf(m, tmax);
        float sum4 = exp2f((v0-mn)*LOG2E) + exp2f((v1-mn)*LOG2E)
                   + exp2f((v2-mn)*LOG2E) + exp2f((v3-mn)*LOG2E);
        lsum = lsum * exp2f((m - mn) * LOG2E) + sum4;
        m = mn;
    }
    // combine the 4 lane-groups (same s = sl at lanes sl, sl+16, sl+32, sl+48)
    #pragma unroll
    for (int off = 16; off < 64; off <<= 1) {
        float mo = __shfl_xor(m, off);
        float lo = __shfl_xor(lsum, off);
        float mn = fmaxf(m, mo);
        lsum = lsum * exp2f((m - mn)*LOG2E) + lo * exp2f((mo - mn)*LOG2E);
        m = mn;
    }
    float inv_l = 1.0f / lsum;

    // ---- phase 2: recompute scores, write probs (f32), accumulate PV ----
    float* prow = probs + (size_t)bh * 2048 * 2048 + (size_t)(s0 + sl) * 2048;
    __bf16* plrow = &pl[wid][sl][0];
    f32x4 accd[4] = {};
    for (int t2 = 0; t2 < 64; ++t2) {     // 32 t per iteration (two 16-tiles)
        const __bf16* kpa = kbase + (size_t)(t2 * 32 + sl) * 1024 + g * 8;
        const __bf16* kpb = kpa + (size_t)16 * 1024;
        bf16x8 kloa = *(const bf16x8*)(kpa);
        bf16x8 khia = *(const bf16x8*)(kpa + 32);
        bf16x8 klob = *(const bf16x8*)(kpb);
        bf16x8 khib = *(const bf16x8*)(kpb + 32);
        f32x4 ca = {0.f,0.f,0.f,0.f}, cb = {0.f,0.f,0.f,0.f};
        ca = mfma16x16x32(kloa, vlo, ca); ca = mfma16x16x32(khia, vhi, ca);
        cb = mfma16x16x32(klob, vlo, cb); cb = mfma16x16x32(khib, vhi, cb);

        f32x4 pa, pb;
        #pragma unroll
        for (int j = 0; j < 4; ++j) {
            pa[j] = exp2f((ca[j]*0.125f - m) * LOG2E) * inv_l;
            pb[j] = exp2f((cb[j]*0.125f - m) * LOG2E) * inv_l;
        }
        *(f32x4*)(prow + t2*32 + g*4)      = pa;   // probs[s][t..t+3], f32
        *(f32x4*)(prow + t2*32 + 16 + g*4) = pb;

        // bounce p through LDS to re-shape lanes for the PV A-operand
        bf16x4 wa, wb;
        wa[0]=(__bf16)pa[0]; wa[1]=(__bf16)pa[1]; wa[2]=(__bf16)pa[2]; wa[3]=(__bf16)pa[3];
        wb[0]=(__bf16)pb[0]; wb[1]=(__bf16)pb[1]; wb[2]=(__bf16)pb[2]; wb[3]=(__bf16)pb[3];
        *(bf16x4*)(plrow + g*4)      = wa;
        *(bf16x4*)(plrow + 16 + g*4) = wb;
        // same-wave LDS RAW; compiler inserts the lgkmcnt wait
        bf16x8 pfrag = *(const bf16x8*)(&pl[wid][sl][g*8]);   // A: row=s(=sl), k=t

        #pragma unroll
        for (int dt = 0; dt < 4; ++dt) {
            bf16x8 qf = *(const bf16x8*)(qtbase + (size_t)(dt*16 + sl) * 2048 + t2*32 + g*8);
            accd[dt] = mfma16x16x32(pfrag, qf, accd[dt]);   // out[s][d]
        }
    }
    // attn (bf16, natural layout) for the final GEMM
    __bf16* abase = attn + ((size_t)(b * 2048 + s0)) * 1024 + h * 64;
    #pragma unroll
    for (int dt = 0; dt < 4; ++dt) {
        #pragma unroll
        for (int r = 0; r < 4; ++r) {
            abase[(size_t)(g*4 + r) * 1024 + dt*16 + sl] = (__bf16)accd[dt][r];
        }
    }
}

// ---------------- Kernel 4: output GEMM  out = attn(bf16) @ wfT + bf -> f32 ----------------
__global__ void __launch_bounds__(256) final_gemm(
    const __bf16* __restrict__ A, const __bf16* __restrict__ Wt,
    const float* __restrict__ bias, float* __restrict__ out)
{
    int lane = threadIdx.x & 63, wid = threadIdx.x >> 6;
    int g = lane >> 4, sl = lane & 15;
    int bm0 = blockIdx.y * 64, bn0 = blockIdx.x * 64;
    int arow = bm0 + wid * 16 + sl;

    f32x4 acc[4] = {};
    const __bf16* ap = A + (size_t)arow * 1024 + g * 8;
    const __bf16* bp0 = Wt + (size_t)(bn0 + sl) * 1024 + g * 8;

    for (int kk = 0; kk < 32; ++kk) {
        bf16x8 a = *(const bf16x8*)(ap);
        ap += 32;
        #pragma unroll
        for (int nt = 0; nt < 4; ++nt) {
            bf16x8 b = *(const bf16x8*)(bp0 + (size_t)nt * 16 * 1024 + kk * 32);
            acc[nt] = mfma16x16x32(a, b, acc[nt]);
        }
    }
    #pragma unroll
    for (int nt = 0; nt < 4; ++nt) {
        int n = bn0 + nt * 16 + sl;
        float bv = bias[n];
        #pragma unroll
        for (int r = 0; r < 4; ++r) {
            int mrow = bm0 + wid * 16 + g * 4 + r;
            out[(size_t)mrow * 1024 + n] = acc[nt][r] + bv;
        }
    }
}

// ---------------- launch ----------------
extern "C" void kernel_launch(void* const* d_in, const int* in_sizes, int n_in,
                              void* d_out, int out_size, void* d_ws, size_t ws_size,
                              hipStream_t stream)
{
    (void)in_sizes; (void)n_in; (void)out_size; (void)ws_size;
    const float* q  = (const float*)d_in[0];
    const float* k  = (const float*)d_in[1];
    const float* v  = (const float*)d_in[2];
    const float* wq = (const float*)d_in[3];
    const float* bq = (const float*)d_in[4];
    const float* wk = (const float*)d_in[5];
    const float* bk = (const float*)d_in[6];
    const float* wv = (const float*)d_in[7];
    const float* bv = (const float*)d_in[8];
    const float* wf = (const float*)d_in[9];
    const float* bf = (const float*)d_in[10];

    char* ws = (char*)d_ws;                     // 40 MB used
    __bf16* wqT = (__bf16*)(ws);                // 2 MB each
    __bf16* wkT = (__bf16*)(ws + (2ull<<20));
    __bf16* wvT = (__bf16*)(ws + (4ull<<20));
    __bf16* wfT = (__bf16*)(ws + (6ull<<20));
    __bf16* Qt  = (__bf16*)(ws + (8ull<<20));   // [B][H][64][2048] bf16, 8 MB
    __bf16* Kp  = (__bf16*)(ws + (16ull<<20));  // [4096][1024] bf16, 8 MB
    __bf16* Vp  = (__bf16*)(ws + (24ull<<20));  // 8 MB
    __bf16* At  = (__bf16*)(ws + (32ull<<20));  // attn, 8 MB

    float* out   = (float*)d_out;
    float* probs = out + (size_t)4096 * 1024;

    wtrans_kernel<<<dim3(32,32,4), dim3(32,8), 0, stream>>>(wq,wk,wv,wf, wqT,wkT,wvT,wfT);
    proj_gemm<<<dim3(16,64), 256, 0, stream>>>(q, wqT, bq, nullptr, Qt);
    proj_gemm<<<dim3(16,64), 256, 0, stream>>>(k, wkT, bk, Kp, nullptr);
    proj_gemm<<<dim3(16,64), 256, 0, stream>>>(v, wvT, bv, Vp, nullptr);
    flash_attn<<<dim3(32,32), 256, 0, stream>>>(Qt, Kp, Vp, probs, At);
    final_gemm<<<dim3(16,64), 256, 0, stream>>>(At, wfT, bf, out);
}

// Round 4
// 1126.238 us; speedup vs baseline: 1.0901x; 1.0901x over previous
//
#include <hip/hip_runtime.h>
#include <hip/hip_bf16.h>
#include <math.h>

// Shapes (fixed): B=2, S=2048, D_EMBED=D_MODEL=1024, H=16, DEPTH=64.
// Reference quirk: scores = V_proj . K_proj^T / 8 ; attn = probs . Q_proj ; out = attn @ wf + bf
// Outputs concatenated: out [2,2048,1024] f32, then probs [2,16,2048,2048] f32.

typedef float f32x4 __attribute__((ext_vector_type(4)));
typedef __bf16 bf16x8 __attribute__((ext_vector_type(8)));
typedef __bf16 bf16x4 __attribute__((ext_vector_type(4)));

#define LOG2E 1.44269504088896340736f
#define K1 0.18033688011112042592f   // 0.125 * log2(e): folds the 1/sqrt(64) scale into exp2

static __device__ __forceinline__ f32x4 mfma16x16x32(bf16x8 a, bf16x8 b, f32x4 c) {
    return __builtin_amdgcn_mfma_f32_16x16x32_bf16(a, b, c, 0, 0, 0);
}

// ---------------- Kernel 1: transpose+cast 4 weight matrices to bf16 [n][k] ----------------
__global__ void __launch_bounds__(256) wtrans_kernel(
    const float* __restrict__ w0, const float* __restrict__ w1,
    const float* __restrict__ w2, const float* __restrict__ w3,
    __bf16* __restrict__ o0, __bf16* __restrict__ o1,
    __bf16* __restrict__ o2, __bf16* __restrict__ o3)
{
    const float* W; __bf16* O;
    switch (blockIdx.z) {
        case 0: W = w0; O = o0; break;
        case 1: W = w1; O = o1; break;
        case 2: W = w2; O = o2; break;
        default: W = w3; O = o3; break;
    }
    __shared__ float tile[32][33];
    int tx = threadIdx.x, ty = threadIdx.y;           // block (32,8)
    int n0 = blockIdx.x * 32, k0 = blockIdx.y * 32;
    #pragma unroll
    for (int j = 0; j < 32; j += 8)
        tile[ty + j][tx] = W[(size_t)(k0 + ty + j) * 1024 + n0 + tx];
    __syncthreads();
    #pragma unroll
    for (int j = 0; j < 32; j += 8)
        O[(size_t)(n0 + ty + j) * 1024 + k0 + tx] = (__bf16)tile[tx][ty + j];
}

// ---------------- Kernel 2: LDS-staged MFMA GEMM -------------------------------------------
// C[4096][1024] = A[4096][1024] @ Wt[1024][1024]^T + bias.  Wt is [n][k] bf16.
// BM=128, BN=64, BK=64. 256 threads = 4 waves (2x2), wave computes 64x32 (4x2 frags).
// Grid (16, 32) = 512 blocks = 2/CU.
// LDS row stride 72 elem = 144 B (16-aligned; frag reads spread exactly 8 dwords/bank).
// MODE: 0 = bf16 natural out, 1 = bf16 per-head-transposed Qt out, 2 = f32 natural out.
// AFMT: 0 = A is bf16, 1 = A is f32 (converted to bf16 while staging into LDS).
template<int MODE, int AFMT>
__global__ void __launch_bounds__(256) bgemm(
    const float* __restrict__ Af, const __bf16* __restrict__ Ab,
    const __bf16* __restrict__ Wt, const float* __restrict__ bias,
    __bf16* __restrict__ obf, float* __restrict__ of)
{
    __shared__ __bf16 As[128][72];
    __shared__ __bf16 Bs[64][72];
    int tid = threadIdx.x;
    int lane = tid & 63, wid = tid >> 6;
    int g = lane >> 4, sl = lane & 15;
    int wr = wid >> 1, wc = wid & 1;
    int m0 = blockIdx.y * 128, n0 = blockIdx.x * 64;

    int srow = tid >> 3;          // 0..31 (bf16 staging: 8 threads x 16B cover a 128B row)
    int scol = (tid & 7) * 8;
    int frow = tid >> 4;          // 0..15 (f32 staging: 16 threads x 16B cover a 256B row)
    int fcol = (tid & 15) * 4;

    f32x4 acc[4][2] = {};

    for (int kt = 0; kt < 16; ++kt) {
        int k0 = kt * 64;
        __syncthreads();                      // previous compute done before overwrite
        if (AFMT == 1) {
            #pragma unroll
            for (int p = 0; p < 8; ++p) {
                int row = p * 16 + frow;
                f32x4 x = *(const f32x4*)&Af[(size_t)(m0 + row) * 1024 + k0 + fcol];
                bf16x4 w;
                w[0] = (__bf16)x[0]; w[1] = (__bf16)x[1];
                w[2] = (__bf16)x[2]; w[3] = (__bf16)x[3];
                *(bf16x4*)&As[row][fcol] = w;
            }
        } else {
            #pragma unroll
            for (int p = 0; p < 4; ++p) {
                int row = p * 32 + srow;
                *(bf16x8*)&As[row][scol] =
                    *(const bf16x8*)&Ab[(size_t)(m0 + row) * 1024 + k0 + scol];
            }
        }
        #pragma unroll
        for (int p = 0; p < 2; ++p) {
            int row = p * 32 + srow;
            *(bf16x8*)&Bs[row][scol] =
                *(const bf16x8*)&Wt[(size_t)(n0 + row) * 1024 + k0 + scol];
        }
        __syncthreads();
        #pragma unroll
        for (int kk = 0; kk < 2; ++kk) {
            bf16x8 af[4], bfr[2];
            #pragma unroll
            for (int mt = 0; mt < 4; ++mt)
                af[mt] = *(const bf16x8*)&As[wr*64 + mt*16 + sl][kk*32 + g*8];
            #pragma unroll
            for (int nt = 0; nt < 2; ++nt)
                bfr[nt] = *(const bf16x8*)&Bs[wc*32 + nt*16 + sl][kk*32 + g*8];
            #pragma unroll
            for (int mt = 0; mt < 4; ++mt)
                #pragma unroll
                for (int nt = 0; nt < 2; ++nt)
                    acc[mt][nt] = mfma16x16x32(af[mt], bfr[nt], acc[mt][nt]);
        }
    }
    // epilogue: C row=(lane>>4)*4+r, col=lane&15 per 16x16 fragment
    #pragma unroll
    for (int nt = 0; nt < 2; ++nt) {
        int n = n0 + wc*32 + nt*16 + sl;
        float bv = bias[n];
        #pragma unroll
        for (int mt = 0; mt < 4; ++mt) {
            #pragma unroll
            for (int r = 0; r < 4; ++r) {
                int mrow = m0 + wr*64 + mt*16 + g*4 + r;
                float vv = acc[mt][nt][r] + bv;
                if (MODE == 1) {
                    int b = mrow >> 11, s = mrow & 2047;
                    int hh = n >> 6, d = n & 63;
                    obf[((size_t)((b*16 + hh)*64 + d))*2048 + s] = (__bf16)vv;
                } else if (MODE == 0) {
                    obf[(size_t)mrow*1024 + n] = (__bf16)vv;
                } else {
                    of[(size_t)mrow*1024 + n] = vv;
                }
            }
        }
    }
}

// ---------------- Kernel 3: fused flash attention (t-split, 8 waves / 512 thr) -------------
// Block: 64 s-rows of one (b,h); 8 waves = 4 row-groups x 2 t-halves (1024 t each).
// Swapped QK^T: c = mfma(K,V) -> lane (g,sl) owns s = sl, t = tile*16 + g*4 + r.
// Halves merge (m,l) and PV partials through LDS. 32 waves/CU (VGPR forced <= 64).
__global__ void __launch_bounds__(512, 8) flash_attn(
    const __bf16* __restrict__ Qt, const __bf16* __restrict__ Kp,
    const __bf16* __restrict__ Vp, float* __restrict__ probs,
    __bf16* __restrict__ attn)
{
    __shared__ float mlbuf[4][2][2][16];   // [rg][half][{m,l}][sl]
    __shared__ float obuf[4][16][68];      // PV partial merge, padded (2-way banks)
    __shared__ __bf16 pl[8][16][40];       // per-wave p bounce, 80B row stride

    int lane = threadIdx.x & 63, wid = threadIdx.x >> 6;
    int g = lane >> 4, sl = lane & 15;
    int rg = wid >> 1, half = wid & 1;
    int bh = blockIdx.y, b = bh >> 4, h = bh & 15;
    int s0 = blockIdx.x * 64 + rg * 16;
    int tb = half * 1024;

    const __bf16* khalf  = Kp + (size_t)b * 2048 * 1024 + h * 64 + (size_t)tb * 1024;
    const __bf16* qtb    = Qt + (size_t)bh * 64 * 2048 + tb;

    const __bf16* vp = Vp + (size_t)b * 2048 * 1024 + h * 64 + (size_t)(s0 + sl) * 1024 + g * 8;
    bf16x8 vlo = *(const bf16x8*)(vp);
    bf16x8 vhi = *(const bf16x8*)(vp + 32);

    // ---- phase 1: online (max, sum) over this half's 1024 t (raw-score domain) ----
    float mraw = -1e30f, lsum = 0.f;
    #pragma unroll 2
    for (int tt = 0; tt < 64; ++tt) {
        const __bf16* kp = khalf + (size_t)(tt * 16 + sl) * 1024 + g * 8;
        bf16x8 klo = *(const bf16x8*)(kp);
        bf16x8 khi = *(const bf16x8*)(kp + 32);
        f32x4 c = {0.f, 0.f, 0.f, 0.f};
        c = mfma16x16x32(klo, vlo, c);
        c = mfma16x16x32(khi, vhi, c);
        float tmax = fmaxf(fmaxf(c[0], c[1]), fmaxf(c[2], c[3]));
        float mn = fmaxf(mraw, tmax);
        float sc = mn * K1;
        float s4 = exp2f(c[0]*K1 - sc) + exp2f(c[1]*K1 - sc)
                 + exp2f(c[2]*K1 - sc) + exp2f(c[3]*K1 - sc);
        lsum = lsum * exp2f(mraw * K1 - sc) + s4;
        mraw = mn;
    }
    // merge the 4 lane-groups (lanes sl, sl+16, sl+32, sl+48 share s = sl)
    #pragma unroll
    for (int off = 16; off < 64; off <<= 1) {
        float mo = __shfl_xor(mraw, off);
        float lo = __shfl_xor(lsum, off);
        float mn = fmaxf(mraw, mo);
        lsum = lsum * exp2f((mraw - mn) * K1) + lo * exp2f((mo - mn) * K1);
        mraw = mn;
    }
    if (g == 0) { mlbuf[rg][half][0][sl] = mraw; mlbuf[rg][half][1][sl] = lsum; }
    __syncthreads();
    {
        float m0h = mlbuf[rg][0][0][sl], l0 = mlbuf[rg][0][1][sl];
        float m1h = mlbuf[rg][1][0][sl], l1 = mlbuf[rg][1][1][sl];
        float mn = fmaxf(m0h, m1h);
        lsum = l0 * exp2f((m0h - mn) * K1) + l1 * exp2f((m1h - mn) * K1);
        mraw = mn;
    }
    float inv_l = 1.0f / lsum;
    float msc = mraw * K1;

    // ---- phase 2: recompute this half's scores, write probs (nt, f32), partial PV ----
    float* prow = probs + (size_t)bh * 2048 * 2048 + (size_t)(s0 + sl) * 2048 + tb;
    __bf16* plrow = &pl[wid][sl][0];
    f32x4 accd[4] = {};
    for (int t2 = 0; t2 < 32; ++t2) {     // 32 t per iteration, tiles serialized for VGPR
        {   // tile A: t = tb + t2*32 + [0,16)
            const __bf16* kpa = khalf + (size_t)(t2 * 32 + sl) * 1024 + g * 8;
            bf16x8 klo = *(const bf16x8*)(kpa);
            bf16x8 khi = *(const bf16x8*)(kpa + 32);
            f32x4 c = {0.f,0.f,0.f,0.f};
            c = mfma16x16x32(klo, vlo, c);
            c = mfma16x16x32(khi, vhi, c);
            f32x4 pa;
            #pragma unroll
            for (int j = 0; j < 4; ++j) pa[j] = exp2f(c[j]*K1 - msc) * inv_l;
            __builtin_nontemporal_store(pa, (f32x4*)(prow + t2*32 + g*4));
            bf16x4 wa;
            wa[0]=(__bf16)pa[0]; wa[1]=(__bf16)pa[1]; wa[2]=(__bf16)pa[2]; wa[3]=(__bf16)pa[3];
            *(bf16x4*)(plrow + g*4) = wa;
        }
        {   // tile B: t = tb + t2*32 + [16,32)
            const __bf16* kpb = khalf + (size_t)(t2 * 32 + 16 + sl) * 1024 + g * 8;
            bf16x8 klo = *(const bf16x8*)(kpb);
            bf16x8 khi = *(const bf16x8*)(kpb + 32);
            f32x4 c = {0.f,0.f,0.f,0.f};
            c = mfma16x16x32(klo, vlo, c);
            c = mfma16x16x32(khi, vhi, c);
            f32x4 pb;
            #pragma unroll
            for (int j = 0; j < 4; ++j) pb[j] = exp2f(c[j]*K1 - msc) * inv_l;
            __builtin_nontemporal_store(pb, (f32x4*)(prow + t2*32 + 16 + g*4));
            bf16x4 wb;
            wb[0]=(__bf16)pb[0]; wb[1]=(__bf16)pb[1]; wb[2]=(__bf16)pb[2]; wb[3]=(__bf16)pb[3];
            *(bf16x4*)(plrow + 16 + g*4) = wb;
        }
        // same-wave LDS RAW; compiler inserts the lgkmcnt wait
        bf16x8 pfrag = *(const bf16x8*)(&pl[wid][sl][g*8]);   // A: row=s(=sl), k=t
        #pragma unroll
        for (int dt = 0; dt < 4; ++dt) {
            bf16x8 qf = *(const bf16x8*)(qtb + (size_t)(dt*16 + sl) * 2048 + t2*32 + g*8);
            accd[dt] = mfma16x16x32(pfrag, qf, accd[dt]);     // out[s][d] partial (this half)
        }
    }

    // ---- PV merge across halves, then write attn (bf16 natural) ----
    if (half == 0) {
        #pragma unroll
        for (int dt = 0; dt < 4; ++dt)
            #pragma unroll
            for (int r = 0; r < 4; ++r)
                obuf[rg][g*4 + r][dt*16 + sl] = accd[dt][r];
    }
    __syncthreads();
    if (half == 1) {
        __bf16* abase = attn + ((size_t)(b * 2048 + s0)) * 1024 + h * 64;
        #pragma unroll
        for (int dt = 0; dt < 4; ++dt)
            #pragma unroll
            for (int r = 0; r < 4; ++r)
                abase[(size_t)(g*4 + r) * 1024 + dt*16 + sl] =
                    (__bf16)(obuf[rg][g*4 + r][dt*16 + sl] + accd[dt][r]);
    }
}

// ---------------- launch ----------------
extern "C" void kernel_launch(void* const* d_in, const int* in_sizes, int n_in,
                              void* d_out, int out_size, void* d_ws, size_t ws_size,
                              hipStream_t stream)
{
    (void)in_sizes; (void)n_in; (void)out_size; (void)ws_size;
    const float* q  = (const float*)d_in[0];
    const float* k  = (const float*)d_in[1];
    const float* v  = (const float*)d_in[2];
    const float* wq = (const float*)d_in[3];
    const float* bq = (const float*)d_in[4];
    const float* wk = (const float*)d_in[5];
    const float* bk = (const float*)d_in[6];
    const float* wv = (const float*)d_in[7];
    const float* bv = (const float*)d_in[8];
    const float* wf = (const float*)d_in[9];
    const float* bf = (const float*)d_in[10];

    char* ws = (char*)d_ws;                     // 40 MB used (same footprint as round 0)
    __bf16* wqT = (__bf16*)(ws);                // 2 MB each
    __bf16* wkT = (__bf16*)(ws + (2ull<<20));
    __bf16* wvT = (__bf16*)(ws + (4ull<<20));
    __bf16* wfT = (__bf16*)(ws + (6ull<<20));
    __bf16* Qt  = (__bf16*)(ws + (8ull<<20));   // [B][H][64][2048] bf16, 8 MB
    __bf16* Kp  = (__bf16*)(ws + (16ull<<20));  // [4096][1024] bf16, 8 MB
    __bf16* Vp  = (__bf16*)(ws + (24ull<<20));  // 8 MB
    __bf16* At  = (__bf16*)(ws + (32ull<<20));  // attn, 8 MB

    float* out   = (float*)d_out;
    float* probs = out + (size_t)4096 * 1024;

    dim3 gg(16, 32);
    wtrans_kernel<<<dim3(32,32,4), dim3(32,8), 0, stream>>>(wq,wk,wv,wf, wqT,wkT,wvT,wfT);
    bgemm<1,1><<<gg, 256, 0, stream>>>(q, nullptr, wqT, bq, Qt, nullptr);
    bgemm<0,1><<<gg, 256, 0, stream>>>(k, nullptr, wkT, bk, Kp, nullptr);
    bgemm<0,1><<<gg, 256, 0, stream>>>(v, nullptr, wvT, bv, Vp, nullptr);
    flash_attn<<<dim3(32,32), 512, 0, stream>>>(Qt, Kp, Vp, probs, At);
    bgemm<2,0><<<gg, 256, 0, stream>>>(nullptr, At, wfT, bf, nullptr, out);
}